// Round 2
// baseline (1415.467 us; speedup 1.0000x reference)
//
#include <hip/hip_runtime.h>
#include <math.h>

#define DD   128
#define SS   16
#define NL   2
#define GDIM 14
#define NN   8

__device__ __forceinline__ float softplus_f(float x) {
    return fmaxf(x, 0.f) + log1pf(expf(-fabsf(x)));
}

extern "C" __global__ void __launch_bounds__(128)
ssm_fused(const float* __restrict__ xyz, const float* __restrict__ scl,
          const float* __restrict__ rotp, const float* __restrict__ opa,
          const float* __restrict__ colp,
          const float* __restrict__ t_arr, const float* __restrict__ tstamp,
          const float* __restrict__ inW, const float* __restrict__ inB,
          const float* __restrict__ lnG, const float* __restrict__ lnB,
          const float* __restrict__ dtW, const float* __restrict__ dtB,
          const float* __restrict__ BW, const float* __restrict__ CW,
          const float* __restrict__ Alog, const float* __restrict__ Dskp,
          const float* __restrict__ outW, const float* __restrict__ outB,
          const float* __restrict__ teW1, const float* __restrict__ teB1,
          const float* __restrict__ teW2, const float* __restrict__ teB2,
          const float* __restrict__ opW, const float* __restrict__ opB,
          float* __restrict__ out, int M, int Pb)
{
    const int m    = blockIdx.x;
    const int d    = threadIdx.x;   // channel 0..127
    const int lane = d & 63;
    const int wv   = d >> 6;

    __shared__ float params_s[NN][GDIM];
    __shared__ float xn_s[NN][DD];        // 4 KB
    __shared__ float y_s[NN][2*DD];       // 8 KB
    __shared__ float bc_s[2][2][NN][SS];  // [dir][B/C][n][s] 2 KB
    __shared__ float red_s[2][2][NN];     // [wave][sum/sq][n]
    __shared__ float vec_s[DD];
    __shared__ float outg_s[GDIM];

    // ---- stage per-point params (n, g) ----
    if (d < NN*GDIM) {
        const int n = d / GDIM, g = d % GDIM;
        float v;
        if (g < 3)       v = xyz [((size_t)n*M + m)*3 + g];
        else if (g < 6)  v = scl [((size_t)n*M + m)*3 + (g-3)];
        else if (g < 10) v = rotp[((size_t)n*M + m)*4 + (g-6)];
        else if (g < 11) v = opa [ (size_t)n*M + m];
        else             v = colp[((size_t)n*M + m)*3 + (g-11)];
        params_s[n][g] = v;
    }
    __syncthreads();

    // ---- input projection + positional encoding ----
    float h[NN];
    {
        const float hb = inB[d];
        #pragma unroll
        for (int n = 0; n < NN; ++n) h[n] = hb;
        #pragma unroll
        for (int g = 0; g < GDIM; ++g) {
            const float w = inW[g*DD + d];
            #pragma unroll
            for (int n = 0; n < NN; ++n)
                h[n] = fmaf(params_s[n][g], w, h[n]);
        }
        const int j = d & 63;
        const float freq = expf(-logf(10000.f) * (float)j * (1.f/64.f));
        #pragma unroll
        for (int n = 0; n < NN; ++n) {
            const float ang = tstamp[n] * freq;
            h[n] += (d < 64) ? sinf(ang) : cosf(ang);
        }
    }

    // ---- layers ----
    #pragma unroll
    for (int l = 0; l < NL; ++l) {
        // ===== LayerNorm over d for each n =====
        float sum[NN], sq[NN];
        #pragma unroll
        for (int n = 0; n < NN; ++n) { sum[n] = h[n]; sq[n] = h[n]*h[n]; }
        #pragma unroll
        for (int off = 32; off > 0; off >>= 1) {
            #pragma unroll
            for (int n = 0; n < NN; ++n) {
                sum[n] += __shfl_xor(sum[n], off);
                sq[n]  += __shfl_xor(sq[n],  off);
            }
        }
        if (lane == 0) {
            #pragma unroll
            for (int n = 0; n < NN; ++n) { red_s[wv][0][n] = sum[n]; red_s[wv][1][n] = sq[n]; }
        }
        __syncthreads();                                      // B1
        float xn[NN];
        {
            const float gg = lnG[l*DD + d], bb = lnB[l*DD + d];
            #pragma unroll
            for (int n = 0; n < NN; ++n) {
                const float s0 = red_s[0][0][n] + red_s[1][0][n];
                const float s1 = red_s[0][1][n] + red_s[1][1][n];
                const float mean = s0 * (1.f/128.f);
                float var = s1 * (1.f/128.f) - mean*mean;
                const float inv = rsqrtf(fmaxf(var, 0.f) + 1e-5f);
                xn[n] = fmaf((h[n]-mean)*inv, gg, bb);
                xn_s[n][d] = xn[n];
            }
        }
        __syncthreads();                                      // B2

        // ===== dt projection, both directions fused =====
        float dtv[2][NN];
        {
            const float b0 = dtB[(l*2+0)*DD + d], b1 = dtB[(l*2+1)*DD + d];
            #pragma unroll
            for (int n = 0; n < NN; ++n) { dtv[0][n] = b0; dtv[1][n] = b1; }
            const float* W0 = dtW + (size_t)(l*2+0)*DD*DD;
            const float* W1 = dtW + (size_t)(l*2+1)*DD*DD;
            for (int k = 0; k < DD; k += 4) {
                float w0[4], w1[4];
                #pragma unroll
                for (int q = 0; q < 4; ++q) { w0[q] = W0[(k+q)*DD + d]; w1[q] = W1[(k+q)*DD + d]; }
                #pragma unroll
                for (int n = 0; n < NN; ++n) {
                    const float4 x4 = *(const float4*)&xn_s[n][k];
                    dtv[0][n] = fmaf(x4.x, w0[0], dtv[0][n]);
                    dtv[0][n] = fmaf(x4.y, w0[1], dtv[0][n]);
                    dtv[0][n] = fmaf(x4.z, w0[2], dtv[0][n]);
                    dtv[0][n] = fmaf(x4.w, w0[3], dtv[0][n]);
                    dtv[1][n] = fmaf(x4.x, w1[0], dtv[1][n]);
                    dtv[1][n] = fmaf(x4.y, w1[1], dtv[1][n]);
                    dtv[1][n] = fmaf(x4.z, w1[2], dtv[1][n]);
                    dtv[1][n] = fmaf(x4.w, w1[3], dtv[1][n]);
                }
            }
            #pragma unroll
            for (int dir = 0; dir < 2; ++dir)
                #pragma unroll
                for (int n = 0; n < NN; ++n) dtv[dir][n] = softplus_f(dtv[dir][n]);
        }

        // ===== B/C projections: thread = (n, s) layout =====
        {
            const int nb = d >> 4, sb = d & 15;
            float bm0 = 0.f, cm0 = 0.f, bm1 = 0.f, cm1 = 0.f;
            const float* BW0 = BW + (size_t)(l*2+0)*DD*SS;
            const float* BW1 = BW + (size_t)(l*2+1)*DD*SS;
            const float* CW0 = CW + (size_t)(l*2+0)*DD*SS;
            const float* CW1 = CW + (size_t)(l*2+1)*DD*SS;
            for (int k = 0; k < DD; k += 4) {
                const float4 x4 = *(const float4*)&xn_s[nb][k];
                const float xv[4] = {x4.x, x4.y, x4.z, x4.w};
                #pragma unroll
                for (int q = 0; q < 4; ++q) {
                    bm0 = fmaf(xv[q], BW0[(k+q)*SS + sb], bm0);
                    bm1 = fmaf(xv[q], BW1[(k+q)*SS + sb], bm1);
                    cm0 = fmaf(xv[q], CW0[(k+q)*SS + sb], cm0);
                    cm1 = fmaf(xv[q], CW1[(k+q)*SS + sb], cm1);
                }
            }
            bc_s[0][0][nb][sb] = bm0;  bc_s[0][1][nb][sb] = cm0;
            bc_s[1][0][nb][sb] = bm1;  bc_s[1][1][nb][sb] = cm1;
        }
        __syncthreads();                                      // B3

        // ===== SSM scan, both directions (fully unrolled) =====
        #pragma unroll
        for (int dir = 0; dir < 2; ++dir) {
            float Ar[SS];
            #pragma unroll
            for (int s = 0; s < SS; ++s)
                Ar[s] = -expf(Alog[((size_t)(l*2+dir)*DD + d)*SS + s]);
            const float dsk = Dskp[(l*2+dir)*DD + d];
            float st[SS];
            #pragma unroll
            for (int s = 0; s < SS; ++s) st[s] = 0.f;
            #pragma unroll
            for (int t8 = 0; t8 < NN; ++t8) {
                const int n = dir ? (NN-1-t8) : t8;
                const float dtc = dtv[dir][n];
                const float xv  = xn[n];
                const float dx  = dtc * xv;
                float y = dsk * xv;
                #pragma unroll
                for (int s4 = 0; s4 < SS; s4 += 4) {
                    const float4 Bv = *(const float4*)&bc_s[dir][0][n][s4];
                    const float4 Cv = *(const float4*)&bc_s[dir][1][n][s4];
                    st[s4+0] = fmaf(__expf(Ar[s4+0]*dtc), st[s4+0], dx*Bv.x);
                    y = fmaf(st[s4+0], Cv.x, y);
                    st[s4+1] = fmaf(__expf(Ar[s4+1]*dtc), st[s4+1], dx*Bv.y);
                    y = fmaf(st[s4+1], Cv.y, y);
                    st[s4+2] = fmaf(__expf(Ar[s4+2]*dtc), st[s4+2], dx*Bv.z);
                    y = fmaf(st[s4+2], Cv.z, y);
                    st[s4+3] = fmaf(__expf(Ar[s4+3]*dtc), st[s4+3], dx*Bv.w);
                    y = fmaf(st[s4+3], Cv.w, y);
                }
                y_s[n][dir*DD + d] = y;
            }
        }
        __syncthreads();                                      // B4

        // ===== output projection (K = 256) + residual =====
        {
            const float* oW = outW + (size_t)l*2*DD*DD;
            const float ob = outB[l*DD + d];
            float acc[NN];
            #pragma unroll
            for (int n = 0; n < NN; ++n) acc[n] = ob;
            for (int k = 0; k < 2*DD; k += 4) {
                float w[4];
                #pragma unroll
                for (int q = 0; q < 4; ++q) w[q] = oW[(k+q)*DD + d];
                #pragma unroll
                for (int n = 0; n < NN; ++n) {
                    const float4 y4 = *(const float4*)&y_s[n][k];
                    acc[n] = fmaf(y4.x, w[0], acc[n]);
                    acc[n] = fmaf(y4.y, w[1], acc[n]);
                    acc[n] = fmaf(y4.z, w[2], acc[n]);
                    acc[n] = fmaf(y4.w, w[3], acc[n]);
                }
            }
            #pragma unroll
            for (int n = 0; n < NN; ++n) h[n] += acc[n];
        }
        __syncthreads();                                      // B5 (protect y_s/xn_s reuse)
    }

    // ---- time interpolation ----
    const int bidx = m / Pb;
    const float tv = t_arr[bidx];
    const float tn = tv * (float)(NN - 1);
    int il = (int)floorf(tn);
    il = il < 0 ? 0 : (il > NN-2 ? NN-2 : il);
    const float alpha = tn - (float)il;
    float hlow = 0.f, hhigh = 0.f;
    #pragma unroll
    for (int n = 0; n < NN; ++n) {
        if (n == il)     hlow  = h[n];
        if (n == il + 1) hhigh = h[n];
    }
    float hi = (1.f - alpha)*hlow + alpha*hhigh;

    // ---- time-embedding MLP ----
    {
        const float u  = fmaf(tv, teW1[d], teB1[d]);
        vec_s[d] = u / (1.f + expf(-u));   // silu
    }
    __syncthreads();
    {
        float acc = teB2[d];
        for (int k = 0; k < DD; k += 4) {
            const float4 s4 = *(const float4*)&vec_s[k];
            acc = fmaf(s4.x, teW2[(k+0)*DD + d], acc);
            acc = fmaf(s4.y, teW2[(k+1)*DD + d], acc);
            acc = fmaf(s4.z, teW2[(k+2)*DD + d], acc);
            acc = fmaf(s4.w, teW2[(k+3)*DD + d], acc);
        }
        hi += acc;
    }
    __syncthreads();           // all reads of vec_s (silu) done
    vec_s[d] = hi;
    __syncthreads();

    // ---- final 14-wide projection: thread = (g, j) with 8-lane reduce ----
    if (d < GDIM*8) {
        const int g = d >> 3, j = d & 7;
        float part = 0.f;
        #pragma unroll
        for (int q = 0; q < 16; ++q)
            part = fmaf(vec_s[j + 8*q], opW[(j + 8*q)*GDIM + g], part);
        part += __shfl_xor(part, 4);
        part += __shfl_xor(part, 2);
        part += __shfl_xor(part, 1);
        if (j == 0) outg_s[g] = part + opB[g];
    }
    __syncthreads();

    // ---- post-process + store ----
    if (d < GDIM) {
        const int g = d;
        const float v = outg_s[g];
        float r;
        if (g < 3)        r = v;
        else if (g < 6)   r = softplus_f(v);
        else if (g < 10) {
            const float q0 = outg_s[6], q1 = outg_s[7], q2 = outg_s[8], q3 = outg_s[9];
            const float nrm = sqrtf(fmaf(q0,q0, fmaf(q1,q1, fmaf(q2,q2, q3*q3))));
            r = v / fmaxf(nrm, 1e-12f);
        } else {
            r = 1.f / (1.f + expf(-v));
        }
        out[(size_t)m * GDIM + g] = r;
    }
}

extern "C" void kernel_launch(void* const* d_in, const int* in_sizes, int n_in,
                              void* d_out, int out_size, void* d_ws, size_t ws_size,
                              hipStream_t stream) {
    const float* xyz   = (const float*)d_in[0];
    const float* scl   = (const float*)d_in[1];
    const float* rotp  = (const float*)d_in[2];
    const float* opa   = (const float*)d_in[3];
    const float* colp  = (const float*)d_in[4];
    const float* t_arr = (const float*)d_in[5];
    const float* tstmp = (const float*)d_in[6];
    const float* inW   = (const float*)d_in[7];
    const float* inB   = (const float*)d_in[8];
    const float* lnG   = (const float*)d_in[9];
    const float* lnB   = (const float*)d_in[10];
    const float* dtW   = (const float*)d_in[11];
    const float* dtB   = (const float*)d_in[12];
    const float* BW    = (const float*)d_in[13];
    const float* CW    = (const float*)d_in[14];
    const float* Alog  = (const float*)d_in[15];
    const float* Dskp  = (const float*)d_in[16];
    const float* outW  = (const float*)d_in[17];
    const float* outB  = (const float*)d_in[18];
    const float* teW1  = (const float*)d_in[19];
    const float* teB1  = (const float*)d_in[20];
    const float* teW2  = (const float*)d_in[21];
    const float* teB2  = (const float*)d_in[22];
    const float* opW   = (const float*)d_in[23];
    const float* opB   = (const float*)d_in[24];

    const int N = in_sizes[6];             // 8 timesteps
    const int M = in_sizes[3] / N;         // opacity is (N,B,P,1) -> M = B*P
    const int B = in_sizes[5];             // t is (B,)
    const int Pb = M / B;
    (void)N; (void)out_size; (void)d_ws; (void)ws_size; (void)n_in;

    hipLaunchKernelGGL(ssm_fused, dim3(M), dim3(128), 0, stream,
                       xyz, scl, rotp, opa, colp, t_arr, tstmp,
                       inW, inB, lnG, lnB, dtW, dtB, BW, CW, Alog, Dskp,
                       outW, outB, teW1, teB1, teW2, teB2, opW, opB,
                       (float*)d_out, M, Pb);
}

// Round 3
// 910.210 us; speedup vs baseline: 1.5551x; 1.5551x over previous
//
#include <hip/hip_runtime.h>
#include <math.h>

#define DD   128
#define SS   16
#define NL   2
#define GDIM 14
#define NN   8

typedef short  s16x8 __attribute__((ext_vector_type(8)));
typedef float  f32x4 __attribute__((ext_vector_type(4)));
typedef unsigned short ushort_t;

// ws layout (ushort elements):
//   inWt  [128 col][32 k]        @ 0       (4096)   k padded 14->32 with zeros
//   dtWt  [2 l][256 col][128 k]  @ 4096    (65536)  col = dir*128 + d
//   bcWt  [2 l][64 col][128 k]   @ 69632   (16384)  col = dir*32 + which*16 + s (which: 0=B,1=C)
//   outWt [2 l][128 col][256 k]  @ 86016   (65536)
#define WS_INW   0
#define WS_DTW   4096
#define WS_BCW   69632
#define WS_OUTW  86016
#define WS_TOTAL 151552

__device__ __forceinline__ unsigned short f2bf(float f) {
    unsigned u = __float_as_uint(f);
    u += 0x7fffu + ((u >> 16) & 1u);     // RNE
    return (unsigned short)(u >> 16);
}

__device__ __forceinline__ float softplus_f(float x) {
    return fmaxf(x, 0.f) + log1pf(expf(-fabsf(x)));
}

extern "C" __global__ void __launch_bounds__(256)
prep_weights(const float* __restrict__ inW, const float* __restrict__ dtW,
             const float* __restrict__ BW,  const float* __restrict__ CW,
             const float* __restrict__ outW, ushort_t* __restrict__ ws)
{
    int i = blockIdx.x * 256 + threadIdx.x;
    if (i < 4096) {                               // inWt [d][k]
        int d = i >> 5, k = i & 31;
        ws[WS_INW + i] = (k < GDIM) ? f2bf(inW[k * DD + d]) : (ushort_t)0;
        return;
    }
    i -= 4096;
    if (i < 65536) {                              // dtWt [l][col][k]
        int l = i >> 15, r = i & 32767;
        int col = r >> 7, k = r & 127;
        int dir = col >> 7, d = col & 127;
        ws[WS_DTW + (i & 65535) + (i >= 65536 ? 0 : 0)] = 0; // (placeholder removed below)
        ws[WS_DTW + ((l << 15) | r)] = f2bf(dtW[((size_t)(l * 2 + dir) * DD + k) * DD + d]);
        return;
    }
    i -= 65536;
    if (i < 16384) {                              // bcWt [l][col][k]
        int l = i >> 13, r = i & 8191;
        int col = r >> 7, k = r & 127;
        int dir = col >> 5, which = (col >> 4) & 1, s = col & 15;
        const float* Wsrc = which ? CW : BW;
        ws[WS_BCW + ((l << 13) | r)] = f2bf(Wsrc[((size_t)(l * 2 + dir) * DD + k) * SS + s]);
        return;
    }
    i -= 16384;
    if (i < 65536) {                              // outWt [l][col][k]
        int l = i >> 15, r = i & 32767;
        int col = r >> 8, k = r & 255;
        ws[WS_OUTW + ((l << 15) | r)] = f2bf(outW[((size_t)l * 2 * DD + k) * DD + col]);
    }
}

extern "C" __global__ void __launch_bounds__(256)
ssm_mfma(const float* __restrict__ xyz, const float* __restrict__ scl,
         const float* __restrict__ rotp, const float* __restrict__ opa,
         const float* __restrict__ colp,
         const float* __restrict__ t_arr, const float* __restrict__ tstamp,
         const float* __restrict__ inB,
         const float* __restrict__ lnG, const float* __restrict__ lnB,
         const float* __restrict__ dtB,
         const float* __restrict__ Alog, const float* __restrict__ Dskp,
         const float* __restrict__ outB,
         const float* __restrict__ teW1, const float* __restrict__ teB1,
         const float* __restrict__ teW2, const float* __restrict__ teB2,
         const float* __restrict__ opW, const float* __restrict__ opB,
         const ushort_t* __restrict__ wsu,
         float* __restrict__ out, int M, int Pb)
{
    const int t    = threadIdx.x;
    const int lane = t & 63;
    const int wv   = t >> 6;          // wave 0..3
    const int d    = t & 127;         // channel
    const int p    = t >> 7;          // point-in-block 0..1
    const int m0   = blockIdx.x * 2;
    const int m    = m0 + p;
    const int r16  = lane & 15;
    const int kg   = lane >> 4;

    __shared__ ushort_t Xs[16][136];      // xn bf16, padded (also params at k<32)
    __shared__ ushort_t Ys[16][264];      // y bf16, padded
    __shared__ float    dtres[16][260];   // dt raw (pre-softplus), col = dir*128+d
    __shared__ float    bcres[16][68];    // B/C, col = dir*32+which*16+s
    __shared__ float    pres [16][132];   // projection results (in-proj / out-proj)
    __shared__ float    red  [4][2][NN];  // LN partial sums per wave
    __shared__ float    vec  [2][128];    // te silu
    __shared__ float    hi2  [2][132];    // interpolated h
    __shared__ float    outg [2][16];

    const ushort_t* inWt  = wsu + WS_INW;
    const ushort_t* dtWt  = wsu + WS_DTW;
    const ushort_t* bcWt  = wsu + WS_BCW;
    const ushort_t* outWt = wsu + WS_OUTW;

    // ---- stage params into Xs (bf16), k padded to 32 with zeros ----
    for (int idx = t; idx < 16 * 32; idx += 256) {
        const int row = idx >> 5, k = idx & 31;
        const int pp = row >> 3, n = row & 7;
        const int mm = m0 + pp;
        float v = 0.f;
        if (k < GDIM && mm < M) {
            if (k < 3)       v = xyz [((size_t)n * M + mm) * 3 + k];
            else if (k < 6)  v = scl [((size_t)n * M + mm) * 3 + (k - 3)];
            else if (k < 10) v = rotp[((size_t)n * M + mm) * 4 + (k - 6)];
            else if (k < 11) v = opa [ (size_t)n * M + mm];
            else             v = colp[((size_t)n * M + mm) * 3 + (k - 11)];
        }
        Xs[row][k] = f2bf(v);
    }
    __syncthreads();

    // ---- in-projection MFMA: C[16 x 128] = params[16 x 32] @ inW ----
    {
        const s16x8 a = *(const s16x8*)&Xs[r16][kg * 8];
        #pragma unroll
        for (int ti = 0; ti < 2; ++ti) {
            const int col = (wv * 2 + ti) * 16 + r16;
            const s16x8 b = *(const s16x8*)&inWt[col * 32 + kg * 8];
            f32x4 acc = {0.f, 0.f, 0.f, 0.f};
            acc = __builtin_amdgcn_mfma_f32_16x16x32_bf16(a, b, acc, 0, 0, 0);
            #pragma unroll
            for (int j = 0; j < 4; ++j) pres[kg * 4 + j][col] = acc[j];
        }
    }
    __syncthreads();

    // ---- h = in-proj + bias + positional encoding (fp32 regs) ----
    float h[NN];
    {
        const float hb = inB[d];
        const int j = d & 63;
        const float freq = expf(-logf(10000.f) * (float)j * (1.f / 64.f));
        #pragma unroll
        for (int n = 0; n < NN; ++n) {
            const float ang = tstamp[n] * freq;
            h[n] = pres[p * 8 + n][d] + hb + ((d < 64) ? sinf(ang) : cosf(ang));
        }
    }

    // ================= layers =================
    for (int l = 0; l < NL; ++l) {
        // ---- P0: LayerNorm reduce ----
        float sum[NN], sq[NN];
        #pragma unroll
        for (int n = 0; n < NN; ++n) { sum[n] = h[n]; sq[n] = h[n] * h[n]; }
        #pragma unroll
        for (int off = 32; off > 0; off >>= 1) {
            #pragma unroll
            for (int n = 0; n < NN; ++n) {
                sum[n] += __shfl_xor(sum[n], off);
                sq[n]  += __shfl_xor(sq[n],  off);
            }
        }
        if (lane == 0) {
            #pragma unroll
            for (int n = 0; n < NN; ++n) { red[wv][0][n] = sum[n]; red[wv][1][n] = sq[n]; }
        }
        __syncthreads();                                   // S1

        // ---- P1: xn (fp32 regs) + write bf16 to Xs ----
        float xn[NN];
        {
            const float gg = lnG[l * DD + d], bb = lnB[l * DD + d];
            #pragma unroll
            for (int n = 0; n < NN; ++n) {
                const float s0 = red[2 * p][0][n] + red[2 * p + 1][0][n];
                const float s1 = red[2 * p][1][n] + red[2 * p + 1][1][n];
                const float mean = s0 * (1.f / 128.f);
                float var = s1 * (1.f / 128.f) - mean * mean;
                const float inv = rsqrtf(fmaxf(var, 0.f) + 1e-5f);
                xn[n] = fmaf((h[n] - mean) * inv, gg, bb);
                Xs[p * 8 + n][d] = f2bf(xn[n]);
            }
        }
        __syncthreads();                                   // S2

        // ---- P2: MFMA dt (256 cols) + B/C (64 cols) ----
        {
            s16x8 a[4];
            #pragma unroll
            for (int kc = 0; kc < 4; ++kc)
                a[kc] = *(const s16x8*)&Xs[r16][kc * 32 + kg * 8];

            const ushort_t* dtl = dtWt + l * 32768;
            #pragma unroll
            for (int ti = 0; ti < 4; ++ti) {
                const int col = (wv * 4 + ti) * 16 + r16;
                f32x4 acc = {0.f, 0.f, 0.f, 0.f};
                #pragma unroll
                for (int kc = 0; kc < 4; ++kc) {
                    const s16x8 b = *(const s16x8*)&dtl[col * 128 + kc * 32 + kg * 8];
                    acc = __builtin_amdgcn_mfma_f32_16x16x32_bf16(a[kc], b, acc, 0, 0, 0);
                }
                #pragma unroll
                for (int j = 0; j < 4; ++j) dtres[kg * 4 + j][col] = acc[j];
            }
            const ushort_t* bcl = bcWt + l * 8192;
            {
                const int col = wv * 16 + r16;
                f32x4 acc = {0.f, 0.f, 0.f, 0.f};
                #pragma unroll
                for (int kc = 0; kc < 4; ++kc) {
                    const s16x8 b = *(const s16x8*)&bcl[col * 128 + kc * 32 + kg * 8];
                    acc = __builtin_amdgcn_mfma_f32_16x16x32_bf16(a[kc], b, acc, 0, 0, 0);
                }
                #pragma unroll
                for (int j = 0; j < 4; ++j) bcres[kg * 4 + j][col] = acc[j];
            }
        }
        __syncthreads();                                   // S3

        // ---- P3: softplus(dt) + SSM scan (fp32), write y bf16 ----
        {
            float dtv[2][NN];
            #pragma unroll
            for (int dir = 0; dir < 2; ++dir) {
                const float db = dtB[(l * 2 + dir) * DD + d];
                #pragma unroll
                for (int n = 0; n < NN; ++n)
                    dtv[dir][n] = softplus_f(dtres[p * 8 + n][dir * 128 + d] + db);
            }
            #pragma unroll
            for (int dir = 0; dir < 2; ++dir) {
                float Ar[SS];
                #pragma unroll
                for (int s = 0; s < SS; ++s)
                    Ar[s] = -expf(Alog[((size_t)(l * 2 + dir) * DD + d) * SS + s]);
                const float dsk = Dskp[(l * 2 + dir) * DD + d];
                float st[SS];
                #pragma unroll
                for (int s = 0; s < SS; ++s) st[s] = 0.f;
                #pragma unroll
                for (int t8 = 0; t8 < NN; ++t8) {
                    const int n = dir ? (NN - 1 - t8) : t8;
                    const float dtc = dtv[dir][n];
                    const float xv  = xn[n];
                    const float dx  = dtc * xv;
                    float y = dsk * xv;
                    const float* base = &bcres[p * 8 + n][dir * 32];
                    #pragma unroll
                    for (int s4 = 0; s4 < SS; s4 += 4) {
                        const float4 Bv = *(const float4*)&base[s4];
                        const float4 Cv = *(const float4*)&base[16 + s4];
                        st[s4+0] = fmaf(__expf(Ar[s4+0] * dtc), st[s4+0], dx * Bv.x);
                        y = fmaf(st[s4+0], Cv.x, y);
                        st[s4+1] = fmaf(__expf(Ar[s4+1] * dtc), st[s4+1], dx * Bv.y);
                        y = fmaf(st[s4+1], Cv.y, y);
                        st[s4+2] = fmaf(__expf(Ar[s4+2] * dtc), st[s4+2], dx * Bv.z);
                        y = fmaf(st[s4+2], Cv.z, y);
                        st[s4+3] = fmaf(__expf(Ar[s4+3] * dtc), st[s4+3], dx * Bv.w);
                        y = fmaf(st[s4+3], Cv.w, y);
                    }
                    Ys[p * 8 + n][dir * 128 + d] = f2bf(y);
                }
            }
        }
        __syncthreads();                                   // S4

        // ---- P4: MFMA out-projection: C[16 x 128] = y[16 x 256] @ outW ----
        {
            s16x8 a[8];
            #pragma unroll
            for (int kc = 0; kc < 8; ++kc)
                a[kc] = *(const s16x8*)&Ys[r16][kc * 32 + kg * 8];
            const ushort_t* ol = outWt + l * 32768;
            #pragma unroll
            for (int ti = 0; ti < 2; ++ti) {
                const int col = (wv * 2 + ti) * 16 + r16;
                f32x4 acc = {0.f, 0.f, 0.f, 0.f};
                #pragma unroll
                for (int kc = 0; kc < 8; ++kc) {
                    const s16x8 b = *(const s16x8*)&ol[col * 256 + kc * 32 + kg * 8];
                    acc = __builtin_amdgcn_mfma_f32_16x16x32_bf16(a[kc], b, acc, 0, 0, 0);
                }
                #pragma unroll
                for (int j = 0; j < 4; ++j) pres[kg * 4 + j][col] = acc[j];
            }
        }
        __syncthreads();                                   // S5

        // ---- P5: residual ----
        {
            const float ob = outB[l * DD + d];
            #pragma unroll
            for (int n = 0; n < NN; ++n) h[n] += pres[p * 8 + n][d] + ob;
        }
        // no barrier needed: next writes to pres are behind S2'..S4'
    }

    // ---- time interpolation ----
    const int mc = (m < M) ? m : (M - 1);
    const float tv = t_arr[mc / Pb];
    const float tn = tv * (float)(NN - 1);
    int il = (int)floorf(tn);
    il = il < 0 ? 0 : (il > NN - 2 ? NN - 2 : il);
    const float alpha = tn - (float)il;
    float hlow = 0.f, hhigh = 0.f;
    #pragma unroll
    for (int n = 0; n < NN; ++n) {
        if (n == il)     hlow  = h[n];
        if (n == il + 1) hhigh = h[n];
    }
    float hi = (1.f - alpha) * hlow + alpha * hhigh;

    // ---- time-embedding MLP ----
    {
        const float u = fmaf(tv, teW1[d], teB1[d]);
        vec[p][d] = u / (1.f + expf(-u));
    }
    __syncthreads();
    {
        float acc = teB2[d];
        for (int k = 0; k < DD; k += 4) {
            const float4 s4 = *(const float4*)&vec[p][k];
            acc = fmaf(s4.x, teW2[(k + 0) * DD + d], acc);
            acc = fmaf(s4.y, teW2[(k + 1) * DD + d], acc);
            acc = fmaf(s4.z, teW2[(k + 2) * DD + d], acc);
            acc = fmaf(s4.w, teW2[(k + 3) * DD + d], acc);
        }
        hi += acc;
    }
    __syncthreads();
    hi2[p][d] = hi;
    __syncthreads();

    // ---- final 14-wide projection ----
    if (d < GDIM * 8) {
        const int g = d >> 3, j = d & 7;
        float part = 0.f;
        #pragma unroll
        for (int q = 0; q < 16; ++q)
            part = fmaf(hi2[p][j + 8 * q], opW[(j + 8 * q) * GDIM + g], part);
        part += __shfl_xor(part, 4);
        part += __shfl_xor(part, 2);
        part += __shfl_xor(part, 1);
        if (j == 0) outg[p][g] = part + opB[g];
    }
    __syncthreads();

    // ---- post-process + store ----
    if (d < GDIM && m < M) {
        const int g = d;
        const float v = outg[p][g];
        float r;
        if (g < 3)        r = v;
        else if (g < 6)   r = softplus_f(v);
        else if (g < 10) {
            const float q0 = outg[p][6], q1 = outg[p][7], q2 = outg[p][8], q3 = outg[p][9];
            const float nrm = sqrtf(fmaf(q0,q0, fmaf(q1,q1, fmaf(q2,q2, q3*q3))));
            r = v / fmaxf(nrm, 1e-12f);
        } else {
            r = 1.f / (1.f + expf(-v));
        }
        out[(size_t)m * GDIM + g] = r;
    }
}

extern "C" void kernel_launch(void* const* d_in, const int* in_sizes, int n_in,
                              void* d_out, int out_size, void* d_ws, size_t ws_size,
                              hipStream_t stream) {
    const float* xyz   = (const float*)d_in[0];
    const float* scl   = (const float*)d_in[1];
    const float* rotp  = (const float*)d_in[2];
    const float* opa   = (const float*)d_in[3];
    const float* colp  = (const float*)d_in[4];
    const float* t_arr = (const float*)d_in[5];
    const float* tstmp = (const float*)d_in[6];
    const float* inW   = (const float*)d_in[7];
    const float* inB   = (const float*)d_in[8];
    const float* lnG   = (const float*)d_in[9];
    const float* lnB   = (const float*)d_in[10];
    const float* dtW   = (const float*)d_in[11];
    const float* dtB   = (const float*)d_in[12];
    const float* BW    = (const float*)d_in[13];
    const float* CW    = (const float*)d_in[14];
    const float* Alog  = (const float*)d_in[15];
    const float* Dskp  = (const float*)d_in[16];
    const float* outW  = (const float*)d_in[17];
    const float* outB  = (const float*)d_in[18];
    const float* teW1  = (const float*)d_in[19];
    const float* teB1  = (const float*)d_in[20];
    const float* teW2  = (const float*)d_in[21];
    const float* teB2  = (const float*)d_in[22];
    const float* opW   = (const float*)d_in[23];
    const float* opB   = (const float*)d_in[24];

    const int N  = in_sizes[6];            // 8
    const int M  = in_sizes[3] / N;        // B*P
    const int B  = in_sizes[5];
    const int Pb = M / B;
    (void)out_size; (void)n_in;

    ushort_t* wsu = (ushort_t*)d_ws;
    hipLaunchKernelGGL(prep_weights, dim3((WS_TOTAL + 255) / 256), dim3(256), 0, stream,
                       inW, dtW, BW, CW, outW, wsu);
    hipLaunchKernelGGL(ssm_mfma, dim3((M + 1) / 2), dim3(256), 0, stream,
                       xyz, scl, rotp, opa, colp, t_arr, tstmp,
                       inB, lnG, lnB, dtB, Alog, Dskp, outB,
                       teW1, teB1, teW2, teB2, opW, opB,
                       wsu, (float*)d_out, M, Pb);
}

// Round 4
// 517.099 us; speedup vs baseline: 2.7373x; 1.7602x over previous
//
#include <hip/hip_runtime.h>
#include <math.h>

#define DD   128
#define SS   16
#define NL   2
#define GDIM 14
#define NN   8

typedef short  s16x8 __attribute__((ext_vector_type(8)));
typedef float  f32x4 __attribute__((ext_vector_type(4)));
typedef unsigned short ushort_t;

// ws layout:
//   ushort region:
//     inWt  [128 col][32 k]        @ 0       (4096)
//     dtWt  [2 l][256 col][128 k]  @ 4096    (65536)
//     bcWt  [2 l][64 col][128 k]   @ 69632   (16384)
//     outWt [2 l][128 col][256 k]  @ 86016   (65536)
//   float region @ ushort offset 151552 (byte 303104):
//     A_pre [l*2+dir][16 s][128 d] (8192 floats)  = -exp(Alog)*log2(e)
#define WS_INW   0
#define WS_DTW   4096
#define WS_BCW   69632
#define WS_OUTW  86016
#define WS_USH   151552
#define WS_AFLT  8192

#if __has_builtin(__builtin_amdgcn_exp2f)
#define EXP2(x) __builtin_amdgcn_exp2f(x)
#else
#define EXP2(x) exp2f(x)
#endif

__device__ __forceinline__ unsigned short f2bf(float f) {
    unsigned u = __float_as_uint(f);
    u += 0x7fffu + ((u >> 16) & 1u);     // RNE
    return (unsigned short)(u >> 16);
}

__device__ __forceinline__ float softplus_fast(float x) {
    return fmaxf(x, 0.f) + __logf(1.f + __expf(-fabsf(x)));
}
__device__ __forceinline__ float softplus_precise(float x) {
    return fmaxf(x, 0.f) + log1pf(expf(-fabsf(x)));
}

extern "C" __global__ void __launch_bounds__(256)
prep_weights(const float* __restrict__ inW, const float* __restrict__ dtW,
             const float* __restrict__ BW,  const float* __restrict__ CW,
             const float* __restrict__ outW, const float* __restrict__ Alog,
             ushort_t* __restrict__ ws)
{
    int i = blockIdx.x * 256 + threadIdx.x;
    if (i < 4096) {                               // inWt [d][k]
        int d = i >> 5, k = i & 31;
        ws[WS_INW + i] = (k < GDIM) ? f2bf(inW[k * DD + d]) : (ushort_t)0;
        return;
    }
    i -= 4096;
    if (i < 65536) {                              // dtWt [l][col][k]
        int l = i >> 15, r = i & 32767;
        int col = r >> 7, k = r & 127;
        int dir = col >> 7, d = col & 127;
        ws[WS_DTW + i] = f2bf(dtW[((size_t)(l * 2 + dir) * DD + k) * DD + d]);
        return;
    }
    i -= 65536;
    if (i < 16384) {                              // bcWt [l][col][k]
        int l = i >> 13, r = i & 8191;
        int col = r >> 7, k = r & 127;
        int dir = col >> 5, which = (col >> 4) & 1, s = col & 15;
        const float* Wsrc = which ? CW : BW;
        ws[WS_BCW + i] = f2bf(Wsrc[((size_t)(l * 2 + dir) * DD + k) * SS + s]);
        return;
    }
    i -= 16384;
    if (i < 65536) {                              // outWt [l][col][k]
        int l = i >> 15, r = i & 32767;
        int col = r >> 8, k = r & 255;
        ws[WS_OUTW + i] = f2bf(outW[((size_t)l * 2 * DD + k) * DD + col]);
        return;
    }
    i -= 65536;
    if (i < WS_AFLT) {                            // A_pre [ld][s][d]
        float* wsf = (float*)(ws + WS_USH);
        int ld = i >> 11, r = i & 2047;
        int s = r >> 7, d = r & 127;
        wsf[i] = -expf(Alog[((size_t)ld * DD + d) * SS + s]) * 1.44269504088896f;
    }
}

extern "C" __global__ void __launch_bounds__(256, 4)
ssm_mfma(const float* __restrict__ xyz, const float* __restrict__ scl,
         const float* __restrict__ rotp, const float* __restrict__ opa,
         const float* __restrict__ colp,
         const float* __restrict__ t_arr, const float* __restrict__ tstamp,
         const float* __restrict__ inB,
         const float* __restrict__ lnG, const float* __restrict__ lnB,
         const float* __restrict__ dtB,
         const float* __restrict__ Dskp,
         const float* __restrict__ outB,
         const float* __restrict__ teW1, const float* __restrict__ teB1,
         const float* __restrict__ teW2, const float* __restrict__ teB2,
         const float* __restrict__ opW, const float* __restrict__ opB,
         const ushort_t* __restrict__ wsu,
         float* __restrict__ out, int M, int Pb)
{
    const int t    = threadIdx.x;
    const int lane = t & 63;
    const int wv   = t >> 6;          // wave 0..3
    const int d    = t & 127;         // channel
    const int p    = t >> 7;          // point-in-block 0..1
    const int m0   = blockIdx.x * 2;
    const int m    = m0 + p;
    const int r16  = lane & 15;
    const int kg   = lane >> 4;

    // arenaA: pres f32 [16][132]  ∪  Xs bf16 [16][264] (row stride 264 ushort = 528 B)
    // arenaB: dtres f32 [16][260] ∪  Ys bf16 rows at 520 ushort (= 1040 B) stride
    __shared__ float arenaA[16][132];     // 8448 B
    __shared__ float arenaB[16][260];     // 16640 B
    __shared__ float bcres[16][68];       // 4352 B
    __shared__ float red  [4][2][NN];
    __shared__ float vec  [2][128];
    __shared__ float hi2  [2][132];
    __shared__ float outg [2][16];

    float (*pres)[132] = arenaA;
    ushort_t* XsU = (ushort_t*)&arenaA[0][0];     // [row*264 + k]
    float (*dtres)[260] = arenaB;
    ushort_t* YsU = (ushort_t*)&arenaB[0][0];     // [row*520 + c]

    const ushort_t* inWt  = wsu + WS_INW;
    const ushort_t* dtWt  = wsu + WS_DTW;
    const ushort_t* bcWt  = wsu + WS_BCW;
    const ushort_t* outWt = wsu + WS_OUTW;
    const float*    Apre  = (const float*)(wsu + WS_USH);

    // ---- stage params into Xs (bf16), k padded to 32 with zeros ----
    for (int idx = t; idx < 16 * 32; idx += 256) {
        const int row = idx >> 5, k = idx & 31;
        const int pp = row >> 3, n = row & 7;
        const int mm = m0 + pp;
        float v = 0.f;
        if (k < GDIM && mm < M) {
            if (k < 3)       v = xyz [((size_t)n * M + mm) * 3 + k];
            else if (k < 6)  v = scl [((size_t)n * M + mm) * 3 + (k - 3)];
            else if (k < 10) v = rotp[((size_t)n * M + mm) * 4 + (k - 6)];
            else if (k < 11) v = opa [ (size_t)n * M + mm];
            else             v = colp[((size_t)n * M + mm) * 3 + (k - 11)];
        }
        XsU[row * 264 + k] = f2bf(v);
    }
    __syncthreads();                                       // S0

    // ---- in-projection MFMA (reads Xs, writes pres — same arena: frag first) ----
    {
        const s16x8 a = *(const s16x8*)&XsU[r16 * 264 + kg * 8];
        __syncthreads();                                   // S0b: frags in regs
        #pragma unroll
        for (int ti = 0; ti < 2; ++ti) {
            const int col = (wv * 2 + ti) * 16 + r16;
            const s16x8 b = *(const s16x8*)&inWt[col * 32 + kg * 8];
            f32x4 acc = {0.f, 0.f, 0.f, 0.f};
            acc = __builtin_amdgcn_mfma_f32_16x16x32_bf16(a, b, acc, 0, 0, 0);
            #pragma unroll
            for (int j = 0; j < 4; ++j) pres[kg * 4 + j][col] = acc[j];
        }
    }
    __syncthreads();                                       // S0c

    // ---- h = in-proj + bias + positional encoding ----
    float h[NN];
    {
        const float hb = inB[d];
        const int j = d & 63;
        const float freq = EXP2(-13.2877123795f * (float)j * (1.f / 64.f));
        #pragma unroll
        for (int n = 0; n < NN; ++n) {
            const float ang = tstamp[n] * freq;
            h[n] = pres[p * 8 + n][d] + hb + ((d < 64) ? __sinf(ang) : __cosf(ang));
        }
    }

    // ================= layers =================
    for (int l = 0; l < NL; ++l) {
        // ---- P0: LayerNorm reduce ----
        float sum[NN], sq[NN];
        #pragma unroll
        for (int n = 0; n < NN; ++n) { sum[n] = h[n]; sq[n] = h[n] * h[n]; }
        #pragma unroll
        for (int off = 32; off > 0; off >>= 1) {
            #pragma unroll
            for (int n = 0; n < NN; ++n) {
                sum[n] += __shfl_xor(sum[n], off);
                sq[n]  += __shfl_xor(sq[n],  off);
            }
        }
        if (lane == 0) {
            #pragma unroll
            for (int n = 0; n < NN; ++n) { red[wv][0][n] = sum[n]; red[wv][1][n] = sq[n]; }
        }
        __syncthreads();                                   // S1

        // ---- P1: xn + write bf16 to Xs ----
        float xn[NN];
        {
            const float gg = lnG[l * DD + d], bb = lnB[l * DD + d];
            #pragma unroll
            for (int n = 0; n < NN; ++n) {
                const float s0 = red[2 * p][0][n] + red[2 * p + 1][0][n];
                const float s1 = red[2 * p][1][n] + red[2 * p + 1][1][n];
                const float mean = s0 * (1.f / 128.f);
                float var = s1 * (1.f / 128.f) - mean * mean;
                const float inv = rsqrtf(fmaxf(var, 0.f) + 1e-5f);
                xn[n] = fmaf((h[n] - mean) * inv, gg, bb);
                XsU[(p * 8 + n) * 264 + d] = f2bf(xn[n]);
            }
        }
        __syncthreads();                                   // S2

        // ---- P2: MFMA dt (256 cols) + B/C (64 cols) ----
        {
            s16x8 a[4];
            #pragma unroll
            for (int kc = 0; kc < 4; ++kc)
                a[kc] = *(const s16x8*)&XsU[r16 * 264 + kc * 32 + kg * 8];

            const ushort_t* dtl = dtWt + l * 32768;
            #pragma unroll
            for (int ti = 0; ti < 4; ++ti) {
                const int col = (wv * 4 + ti) * 16 + r16;
                f32x4 acc = {0.f, 0.f, 0.f, 0.f};
                #pragma unroll
                for (int kc = 0; kc < 4; ++kc) {
                    const s16x8 b = *(const s16x8*)&dtl[col * 128 + kc * 32 + kg * 8];
                    acc = __builtin_amdgcn_mfma_f32_16x16x32_bf16(a[kc], b, acc, 0, 0, 0);
                }
                #pragma unroll
                for (int j = 0; j < 4; ++j) dtres[kg * 4 + j][col] = acc[j];
            }
            const ushort_t* bcl = bcWt + l * 8192;
            {
                const int col = wv * 16 + r16;
                f32x4 acc = {0.f, 0.f, 0.f, 0.f};
                #pragma unroll
                for (int kc = 0; kc < 4; ++kc) {
                    const s16x8 b = *(const s16x8*)&bcl[col * 128 + kc * 32 + kg * 8];
                    acc = __builtin_amdgcn_mfma_f32_16x16x32_bf16(a[kc], b, acc, 0, 0, 0);
                }
                #pragma unroll
                for (int j = 0; j < 4; ++j) bcres[kg * 4 + j][col] = acc[j];
            }
        }
        __syncthreads();                                   // S3

        // ---- P3a: softplus(dt) into regs (then Ys may overlay dtres) ----
        float dtv[2][NN];
        #pragma unroll
        for (int dir = 0; dir < 2; ++dir) {
            const float db = dtB[(l * 2 + dir) * DD + d];
            #pragma unroll
            for (int n = 0; n < NN; ++n)
                dtv[dir][n] = softplus_fast(dtres[p * 8 + n][dir * 128 + d] + db);
        }
        __syncthreads();                                   // S3b: all dtres reads done

        // ---- P3b: SSM scan, write y bf16 into Ys (overlaying dtres) ----
        #pragma unroll
        for (int dir = 0; dir < 2; ++dir) {
            const float* Ap = Apre + (size_t)(l * 2 + dir) * SS * DD + d;
            float Ar[SS];
            #pragma unroll
            for (int s = 0; s < SS; ++s) Ar[s] = Ap[s * DD];
            const float dsk = Dskp[(l * 2 + dir) * DD + d];
            float st[SS];
            #pragma unroll
            for (int s = 0; s < SS; ++s) st[s] = 0.f;
            #pragma unroll
            for (int t8 = 0; t8 < NN; ++t8) {
                const int n = dir ? (NN - 1 - t8) : t8;
                const float dtc = dtv[dir][n];
                const float xv  = xn[n];
                const float dx  = dtc * xv;
                float y = dsk * xv;
                const float* base = &bcres[p * 8 + n][dir * 32];
                #pragma unroll
                for (int s4 = 0; s4 < SS; s4 += 4) {
                    const float4 Bv = *(const float4*)&base[s4];
                    const float4 Cv = *(const float4*)&base[16 + s4];
                    st[s4+0] = fmaf(EXP2(Ar[s4+0] * dtc), st[s4+0], dx * Bv.x);
                    y = fmaf(st[s4+0], Cv.x, y);
                    st[s4+1] = fmaf(EXP2(Ar[s4+1] * dtc), st[s4+1], dx * Bv.y);
                    y = fmaf(st[s4+1], Cv.y, y);
                    st[s4+2] = fmaf(EXP2(Ar[s4+2] * dtc), st[s4+2], dx * Bv.z);
                    y = fmaf(st[s4+2], Cv.z, y);
                    st[s4+3] = fmaf(EXP2(Ar[s4+3] * dtc), st[s4+3], dx * Bv.w);
                    y = fmaf(st[s4+3], Cv.w, y);
                }
                YsU[(p * 8 + n) * 520 + dir * 128 + d] = f2bf(y);
            }
        }
        __syncthreads();                                   // S4

        // ---- P4: MFMA out-projection: C[16x128] = y[16x256] @ outW ----
        {
            s16x8 a[8];
            #pragma unroll
            for (int kc = 0; kc < 8; ++kc)
                a[kc] = *(const s16x8*)&YsU[r16 * 520 + kc * 32 + kg * 8];
            const ushort_t* ol = outWt + l * 32768;
            #pragma unroll
            for (int ti = 0; ti < 2; ++ti) {
                const int col = (wv * 2 + ti) * 16 + r16;
                f32x4 acc = {0.f, 0.f, 0.f, 0.f};
                #pragma unroll
                for (int kc = 0; kc < 8; ++kc) {
                    const s16x8 b = *(const s16x8*)&ol[col * 256 + kc * 32 + kg * 8];
                    acc = __builtin_amdgcn_mfma_f32_16x16x32_bf16(a[kc], b, acc, 0, 0, 0);
                }
                #pragma unroll
                for (int j = 0; j < 4; ++j) pres[kg * 4 + j][col] = acc[j];
            }
        }
        __syncthreads();                                   // S5

        // ---- P5: residual ----
        {
            const float ob = outB[l * DD + d];
            #pragma unroll
            for (int n = 0; n < NN; ++n) h[n] += pres[p * 8 + n][d] + ob;
        }
    }

    // ---- time interpolation ----
    const int mc = (m < M) ? m : (M - 1);
    const float tv = t_arr[mc / Pb];
    const float tn = tv * (float)(NN - 1);
    int il = (int)floorf(tn);
    il = il < 0 ? 0 : (il > NN - 2 ? NN - 2 : il);
    const float alpha = tn - (float)il;
    float hlow = 0.f, hhigh = 0.f;
    #pragma unroll
    for (int n = 0; n < NN; ++n) {
        if (n == il)     hlow  = h[n];
        if (n == il + 1) hhigh = h[n];
    }
    float hi = (1.f - alpha) * hlow + alpha * hhigh;

    // ---- time-embedding MLP ----
    {
        const float u = fmaf(tv, teW1[d], teB1[d]);
        vec[p][d] = u / (1.f + __expf(-u));
    }
    __syncthreads();
    {
        float acc = teB2[d];
        for (int k = 0; k < DD; k += 4) {
            const float4 s4 = *(const float4*)&vec[p][k];
            acc = fmaf(s4.x, teW2[(k + 0) * DD + d], acc);
            acc = fmaf(s4.y, teW2[(k + 1) * DD + d], acc);
            acc = fmaf(s4.z, teW2[(k + 2) * DD + d], acc);
            acc = fmaf(s4.w, teW2[(k + 3) * DD + d], acc);
        }
        hi += acc;
    }
    __syncthreads();
    hi2[p][d] = hi;
    __syncthreads();

    // ---- final 14-wide projection ----
    if (d < GDIM * 8) {
        const int g = d >> 3, j = d & 7;
        float part = 0.f;
        #pragma unroll
        for (int q = 0; q < 16; ++q)
            part = fmaf(hi2[p][j + 8 * q], opW[(j + 8 * q) * GDIM + g], part);
        part += __shfl_xor(part, 4);
        part += __shfl_xor(part, 2);
        part += __shfl_xor(part, 1);
        if (j == 0) outg[p][g] = part + opB[g];
    }
    __syncthreads();

    // ---- post-process + store ----
    if (d < GDIM && m < M) {
        const int g = d;
        const float v = outg[p][g];
        float r;
        if (g < 3)        r = v;
        else if (g < 6)   r = softplus_precise(v);
        else if (g < 10) {
            const float q0 = outg[p][6], q1 = outg[p][7], q2 = outg[p][8], q3 = outg[p][9];
            const float nrm = sqrtf(fmaf(q0,q0, fmaf(q1,q1, fmaf(q2,q2, q3*q3))));
            r = v / fmaxf(nrm, 1e-12f);
        } else {
            r = 1.f / (1.f + expf(-v));
        }
        out[(size_t)m * GDIM + g] = r;
    }
}

extern "C" void kernel_launch(void* const* d_in, const int* in_sizes, int n_in,
                              void* d_out, int out_size, void* d_ws, size_t ws_size,
                              hipStream_t stream) {
    const float* xyz   = (const float*)d_in[0];
    const float* scl   = (const float*)d_in[1];
    const float* rotp  = (const float*)d_in[2];
    const float* opa   = (const float*)d_in[3];
    const float* colp  = (const float*)d_in[4];
    const float* t_arr = (const float*)d_in[5];
    const float* tstmp = (const float*)d_in[6];
    const float* inW   = (const float*)d_in[7];
    const float* inB   = (const float*)d_in[8];
    const float* lnG   = (const float*)d_in[9];
    const float* lnB   = (const float*)d_in[10];
    const float* dtW   = (const float*)d_in[11];
    const float* dtB   = (const float*)d_in[12];
    const float* BW    = (const float*)d_in[13];
    const float* CW    = (const float*)d_in[14];
    const float* Alog  = (const float*)d_in[15];
    const float* Dskp  = (const float*)d_in[16];
    const float* outW  = (const float*)d_in[17];
    const float* outB  = (const float*)d_in[18];
    const float* teW1  = (const float*)d_in[19];
    const float* teB1  = (const float*)d_in[20];
    const float* teW2  = (const float*)d_in[21];
    const float* teB2  = (const float*)d_in[22];
    const float* opW   = (const float*)d_in[23];
    const float* opB   = (const float*)d_in[24];

    const int N  = in_sizes[6];            // 8
    const int M  = in_sizes[3] / N;        // B*P
    const int B  = in_sizes[5];
    const int Pb = M / B;
    (void)out_size; (void)n_in;

    ushort_t* wsu = (ushort_t*)d_ws;
    const int prep_elems = WS_USH + WS_AFLT;
    hipLaunchKernelGGL(prep_weights, dim3((prep_elems + 255) / 256), dim3(256), 0, stream,
                       inW, dtW, BW, CW, outW, Alog, wsu);
    hipLaunchKernelGGL(ssm_mfma, dim3((M + 1) / 2), dim3(256), 0, stream,
                       xyz, scl, rotp, opa, colp, t_arr, tstmp,
                       inB, lnG, lnB, dtB, Dskp, outB,
                       teW1, teB1, teW2, teB2, opW, opB,
                       wsu, (float*)d_out, M, Pb);
}